// Round 10
// baseline (53.299 us; speedup 1.0000x reference)
//
#include <hip/hip_runtime.h>

#define HW     (768*768)       // 589824 pixels per plane
#define N4     (HW/4)          // 147456 float4 groups per plane
#define MAXI   33
#define LUTN   (MAXI+1)        // 34 (entry 33 = weight 0)
#define B_IMG  8
#define NTHR   256
// pass1 geometry (unchanged, known-good ~9 us)
#define NBLK1  1536
#define NJ1    3
#define GPB1   (NTHR*NJ1)
#define BPI1   192
// pass2 geometry: 768 blocks = exactly 3/CU (one round), 6 iters, deep reg batch
#define NBLK2  768
#define NJ2    6
#define GPB2   (NTHR*NJ2)      // 1536 groups per block
#define BPI2   96              // blocks per image

// ws: 0 g_counts int[8][33] | 4096 g_lut float[8][34] | 8192 partials float[NBLK2*3]
//     65536 widx byte plane (4.72 MB)

// ---------- Pass 1: ballot histogram + ci-fused widx byte plane ----------
__global__ __launch_bounds__(NTHR, 6) void pass1_count(
    const int* __restrict__ inst, const int* __restrict__ ign,
    const float* __restrict__ gci,
    int* __restrict__ g_counts, uchar4* __restrict__ wbp, int write_bytes)
{
    const int bid  = blockIdx.x;
    const int b    = bid / BPI1;
    const int lane = threadIdx.x & 63;
    const int wv   = threadIdx.x >> 6;
    const int4*   ip  = (const int4*)inst;
    const int4*   gp  = (const int4*)ign;
    const float4* cip = (const float4*)gci;

    int acc = 0;

    #pragma unroll
    for (int j = 0; j < NJ1; ++j) {
        const int g = bid * GPB1 + j * NTHR + threadIdx.x;
        int4   id4 = ip[g];
        int4   g4  = gp[g];
        float4 ci  = cip[g];
        int c0 = (g4.x == 0) ? id4.x : MAXI;
        int c1 = (g4.y == 0) ? id4.y : MAXI;
        int c2 = (g4.z == 0) ? id4.z : MAXI;
        int c3 = (g4.w == 0) ? id4.w : MAXI;
        if (write_bytes) {
            int e0 = (ci.x != 0.f) ? c0 : MAXI;
            int e1 = (ci.y != 0.f) ? c1 : MAXI;
            int e2 = (ci.z != 0.f) ? c2 : MAXI;
            int e3 = (ci.w != 0.f) ? c3 : MAXI;
            wbp[g] = make_uchar4((unsigned char)e0, (unsigned char)e1,
                                 (unsigned char)e2, (unsigned char)e3);
        }
        for (int k = 0; k < MAXI; ++k) {
            int cc = __popcll(__ballot(c0 == k)) + __popcll(__ballot(c1 == k))
                   + __popcll(__ballot(c2 == k)) + __popcll(__ballot(c3 == k));
            acc += (lane == k) ? cc : 0;
        }
    }

    __shared__ int s_cnt[NTHR / 64][MAXI];
    if (lane < MAXI) s_cnt[wv][lane] = acc;
    __syncthreads();
    if (threadIdx.x < MAXI) {
        int t = 0;
        #pragma unroll
        for (int w = 0; w < NTHR / 64; ++w) t += s_cnt[w][threadIdx.x];
        atomicAdd(&g_counts[b * MAXI + threadIdx.x], t);
    }
}

// ---------- LUT build ----------
__global__ __launch_bounds__(64) void build_lut(
    const int* __restrict__ g_counts, float* __restrict__ g_lut)
{
    const int b = blockIdx.x;
    const int k = threadIdx.x;
    int cnt = (k < MAXI) ? g_counts[b * MAXI + k] : 0;
    unsigned long long m = __ballot(k >= 1 && k < MAXI && cnt > 0);
    float n = fmaxf((float)__popcll(m), 1.0f);
    if (k < LUTN) {
        float f = 0.f;
        if (k < MAXI) {
            f = 1.0f / fmaxf((float)cnt, 1.0f);
            if (k > 0) f /= n;
        }
        g_lut[b * LUTN + k] = f;
    }
}

// ---------- Pass 2 (byte-plane path): deep straight-line register batching ----------
__global__ __launch_bounds__(NTHR, 3) void pass2_deep(
    const float* __restrict__ pred, const uchar4* __restrict__ wbp,
    const float* __restrict__ gtR, const float* __restrict__ gts,
    const float* __restrict__ gtc,
    const float* __restrict__ g_lut, float* __restrict__ partials)
{
    const int bid = blockIdx.x;
    const int b   = bid / BPI2;

    __shared__ float lut[LUTN];
    if (threadIdx.x < LUTN) lut[threadIdx.x] = g_lut[b * LUTN + threadIdx.x];
    __syncthreads();

    const float4* p0 = (const float4*)pred + (size_t)(b * 3 + 0) * N4;
    const float4* p1 = (const float4*)pred + (size_t)(b * 3 + 1) * N4;
    const float4* p2 = (const float4*)pred + (size_t)(b * 3 + 2) * N4;
    const float4* Rp = (const float4*)gtR;
    const float4* sp = (const float4*)gts;
    const float4* cp = (const float4*)gtc;

    const int g0 = bid * GPB2 + threadIdx.x;
    const int g1 = g0 + 1 * NTHR;
    const int g2 = g0 + 2 * NTHR;
    const int g3 = g0 + 3 * NTHR;
    const int g4 = g0 + 4 * NTHR;
    const int g5 = g0 + 5 * NTHR;
    const int bn = b * N4;

    // widx bytes for all 6 iterations, then all 24 lut gathers up front
    uchar4 u0 = wbp[g0], u1 = wbp[g1], u2 = wbp[g2];
    uchar4 u3 = wbp[g3], u4 = wbp[g4], u5 = wbp[g5];
    float f00 = lut[u0.x], f01 = lut[u0.y], f02 = lut[u0.z], f03 = lut[u0.w];
    float f10 = lut[u1.x], f11 = lut[u1.y], f12 = lut[u1.z], f13 = lut[u1.w];
    float f20 = lut[u2.x], f21 = lut[u2.y], f22 = lut[u2.z], f23 = lut[u2.w];
    float f30 = lut[u3.x], f31 = lut[u3.y], f32 = lut[u3.z], f33 = lut[u3.w];
    float f40 = lut[u4.x], f41 = lut[u4.y], f42 = lut[u4.z], f43 = lut[u4.w];
    float f50 = lut[u5.x], f51 = lut[u5.y], f52 = lut[u5.z], f53 = lut[u5.w];

    float as = 0.f, ac = 0.f, ar = 0.f;

#define ISSUE(I, G) \
    float4 I##a  = p0[(G) - bn]; \
    float4 I##b  = p1[(G) - bn]; \
    float4 I##r  = p2[(G) - bn]; \
    float4 I##R  = Rp[G]; \
    float4 I##s  = sp[G]; \
    float4 I##c  = cp[G];

#define CONSUME(I, F0, F1, F2, F3) \
    as += F0 * fabsf(I##a.x - I##s.x) + F1 * fabsf(I##a.y - I##s.y) \
        + F2 * fabsf(I##a.z - I##s.z) + F3 * fabsf(I##a.w - I##s.w); \
    ac += F0 * fabsf(I##b.x - I##c.x) + F1 * fabsf(I##b.y - I##c.y) \
        + F2 * fabsf(I##b.z - I##c.z) + F3 * fabsf(I##b.w - I##c.w); \
    ar += F0 * fabsf(I##r.x - __logf(I##R.x + 1.f)) + F1 * fabsf(I##r.y - __logf(I##R.y + 1.f)) \
        + F2 * fabsf(I##r.z - __logf(I##R.z + 1.f)) + F3 * fabsf(I##r.w - __logf(I##R.w + 1.f));

    // straight-line schedule: 24 loads in flight before first consume
    ISSUE(I0, g0)
    ISSUE(I1, g1)
    ISSUE(I2, g2)
    ISSUE(I3, g3)
    CONSUME(I0, f00, f01, f02, f03)
    CONSUME(I1, f10, f11, f12, f13)
    ISSUE(I4, g4)
    ISSUE(I5, g5)
    CONSUME(I2, f20, f21, f22, f23)
    CONSUME(I3, f30, f31, f32, f33)
    CONSUME(I4, f40, f41, f42, f43)
    CONSUME(I5, f50, f51, f52, f53)
#undef ISSUE
#undef CONSUME

    #pragma unroll
    for (int o = 32; o > 0; o >>= 1) {
        as += __shfl_down(as, o);
        ac += __shfl_down(ac, o);
        ar += __shfl_down(ar, o);
    }
    __shared__ float sred[3][NTHR / 64];
    const int wv = threadIdx.x >> 6, lane = threadIdx.x & 63;
    if (lane == 0) { sred[0][wv] = as; sred[1][wv] = ac; sred[2][wv] = ar; }
    __syncthreads();
    if (threadIdx.x == 0) {
        float ts = 0.f, tc = 0.f, tr = 0.f;
        #pragma unroll
        for (int w = 0; w < NTHR / 64; ++w) { ts += sred[0][w]; tc += sred[1][w]; tr += sred[2][w]; }
        float* pp = partials + (size_t)bid * 3;
        pp[0] = ts; pp[1] = tc; pp[2] = tr;
    }
}

// ---------- Pass 2 fallback (raw inputs; correctness only) ----------
__global__ __launch_bounds__(NTHR, 3) void pass2_fallback(
    const float* __restrict__ pred,
    const int* __restrict__ inst, const int* __restrict__ ign,
    const float* __restrict__ gci,
    const float* __restrict__ gtR, const float* __restrict__ gts,
    const float* __restrict__ gtc,
    const float* __restrict__ g_lut, float* __restrict__ partials)
{
    const int bid = blockIdx.x;
    const int b   = bid / BPI2;
    __shared__ float lut[LUTN];
    if (threadIdx.x < LUTN) lut[threadIdx.x] = g_lut[b * LUTN + threadIdx.x];
    __syncthreads();

    const float4* p0 = (const float4*)pred + (size_t)(b * 3 + 0) * N4;
    const float4* p1 = (const float4*)pred + (size_t)(b * 3 + 1) * N4;
    const float4* p2 = (const float4*)pred + (size_t)(b * 3 + 2) * N4;
    const float4* Rp = (const float4*)gtR;
    const float4* sp = (const float4*)gts;
    const float4* cp = (const float4*)gtc;
    const int4*   ipp = (const int4*)inst;
    const int4*   gpp = (const int4*)ign;
    const float4* cip = (const float4*)gci;

    float as = 0.f, ac = 0.f, ar = 0.f;
    for (int j = 0; j < NJ2; ++j) {
        const int g  = bid * GPB2 + j * NTHR + threadIdx.x;
        const int lg = g - b * N4;
        float4 a  = p0[lg];
        float4 bb = p1[lg];
        float4 rr = p2[lg];
        float4 R  = Rp[g];
        float4 si = sp[g];
        float4 co = cp[g];
        int4 id4 = ipp[g]; int4 g4 = gpp[g]; float4 ci = cip[g];
        int w0 = (g4.x == 0 && ci.x != 0.f) ? id4.x : MAXI;
        int w1 = (g4.y == 0 && ci.y != 0.f) ? id4.y : MAXI;
        int w2 = (g4.z == 0 && ci.z != 0.f) ? id4.z : MAXI;
        int w3 = (g4.w == 0 && ci.w != 0.f) ? id4.w : MAXI;
        float f0 = lut[w0], f1 = lut[w1], f2 = lut[w2], f3 = lut[w3];
        as += f0 * fabsf(a.x - si.x) + f1 * fabsf(a.y - si.y)
            + f2 * fabsf(a.z - si.z) + f3 * fabsf(a.w - si.w);
        ac += f0 * fabsf(bb.x - co.x) + f1 * fabsf(bb.y - co.y)
            + f2 * fabsf(bb.z - co.z) + f3 * fabsf(bb.w - co.w);
        ar += f0 * fabsf(rr.x - __logf(R.x + 1.f)) + f1 * fabsf(rr.y - __logf(R.y + 1.f))
            + f2 * fabsf(rr.z - __logf(R.z + 1.f)) + f3 * fabsf(rr.w - __logf(R.w + 1.f));
    }

    #pragma unroll
    for (int o = 32; o > 0; o >>= 1) {
        as += __shfl_down(as, o);
        ac += __shfl_down(ac, o);
        ar += __shfl_down(ar, o);
    }
    __shared__ float sred[3][NTHR / 64];
    const int wv = threadIdx.x >> 6, lane = threadIdx.x & 63;
    if (lane == 0) { sred[0][wv] = as; sred[1][wv] = ac; sred[2][wv] = ar; }
    __syncthreads();
    if (threadIdx.x == 0) {
        float ts = 0.f, tc = 0.f, tr = 0.f;
        #pragma unroll
        for (int w = 0; w < NTHR / 64; ++w) { ts += sred[0][w]; tc += sred[1][w]; tr += sred[2][w]; }
        float* pp = partials + (size_t)bid * 3;
        pp[0] = ts; pp[1] = tc; pp[2] = tr;
    }
}

// ---------- Finalize: deterministic reduce of 96 block-partials per image ----------
__global__ __launch_bounds__(NTHR) void finalize(
    const float* __restrict__ partials, float* __restrict__ out)
{
    const int b = blockIdx.x;
    float s = 0.f, c = 0.f, r = 0.f;
    if (threadIdx.x < BPI2) {
        const float* pp = partials + (size_t)(b * BPI2 + threadIdx.x) * 3;
        s = pp[0]; c = pp[1]; r = pp[2];
    }
    #pragma unroll
    for (int o = 32; o > 0; o >>= 1) {
        s += __shfl_down(s, o);
        c += __shfl_down(c, o);
        r += __shfl_down(r, o);
    }
    __shared__ float sr[3][NTHR / 64];
    const int wv = threadIdx.x >> 6, lane = threadIdx.x & 63;
    if (lane == 0) { sr[0][wv] = s; sr[1][wv] = c; sr[2][wv] = r; }
    __syncthreads();
    if (threadIdx.x == 0) {
        float ts = 0.f, tc = 0.f, tr = 0.f;
        #pragma unroll
        for (int w = 0; w < NTHR / 64; ++w) { ts += sr[0][w]; tc += sr[1][w]; tr += sr[2][w]; }
        float tot = ts + tc + tr;
        out[     b] = tot;
        out[ 8 + b] = 0.f;
        out[16 + b] = tot;
        out[24 + b] = 0.f;
        out[32 + b] = ts;
        out[40 + b] = tc;
        out[48 + b] = tr;
        out[56 + b] = 0.f;
    }
}

extern "C" void kernel_launch(void* const* d_in, const int* in_sizes, int n_in,
                              void* d_out, int out_size, void* d_ws, size_t ws_size,
                              hipStream_t stream) {
    const float* pred = (const float*)d_in[0];
    const int*   inst = (const int*)d_in[1];
    // d_in[2] = label (unused by the reference)
    const float* gtR  = (const float*)d_in[3];
    const float* gts  = (const float*)d_in[4];
    const float* gtc  = (const float*)d_in[5];
    const float* gci  = (const float*)d_in[6];
    const int*   ign  = (const int*)d_in[7];
    float* out = (float*)d_out;

    int*    g_counts = (int*)d_ws;
    float*  g_lut    = (float*)((char*)d_ws + 4096);
    float*  partials = (float*)((char*)d_ws + 8192);      // 768*3*4 = 9216 B
    uchar4* wbp      = (uchar4*)((char*)d_ws + 65536);    // 4.72 MB
    const size_t need_bytes = 65536 + (size_t)B_IMG * HW;
    const int use_bytes = (ws_size >= need_bytes) ? 1 : 0;

    hipMemsetAsync(g_counts, 0, B_IMG * MAXI * sizeof(int), stream);

    pass1_count<<<NBLK1, NTHR, 0, stream>>>(inst, ign, gci, g_counts, wbp, use_bytes);
    build_lut<<<B_IMG, 64, 0, stream>>>(g_counts, g_lut);
    if (use_bytes)
        pass2_deep<<<NBLK2, NTHR, 0, stream>>>(pred, wbp, gtR, gts, gtc, g_lut, partials);
    else
        pass2_fallback<<<NBLK2, NTHR, 0, stream>>>(pred, inst, ign, gci,
                                                   gtR, gts, gtc, g_lut, partials);
    finalize<<<B_IMG, NTHR, 0, stream>>>(partials, out);
}